// Round 5
// baseline (123.649 us; speedup 1.0000x reference)
//
#include <hip/hip_runtime.h>
#include <math.h>

#define LOG2PI_F 1.8378770664093453f
#define LOG2E_F  1.4426950408889634f
#define LN2_F    0.6931471805599453f
#define EXP_NEG1 0.36787944117144233f

#define ROWF 52      // floats per AC row: a[16] b[16] c[16] prod pad[3]
#define JSP  32      // j-chunk slabs (k_pair grid.y)
#define JCW  16      // j-rows per wave = B / JSP / 4

__device__ __forceinline__ float exp2_(float x) { return __builtin_amdgcn_exp2f(x); }
__device__ __forceinline__ float log2_(float x) { return __builtin_amdgcn_logf(x); }

// ws layout (floats):
//   reconPart[512]            @ 0
//   prepPart [256]            @ 512   (128 blocks x {lqzx, lprior})
//   logsPart [64]             @ 768   (32 blocks x {lqz, lqzp})
//   AC       [B*52]           @ 1024  (16B aligned)
//   Racc     [JSP*17*B]       @ 1024 + B*52   (slab s, component c, row i)
// No memset needed: every location read is written first within this launch.

__global__ __launch_bounds__(256) void k_recon(const float4* __restrict__ x,
                                               const float4* __restrict__ r,
                                               float* __restrict__ part, int n4) {
    float s = 0.0f;
    for (int idx = blockIdx.x * 256 + threadIdx.x; idx < n4; idx += gridDim.x * 256) {
        float4 a = x[idx], b = r[idx];
        s += fabsf(a.x - b.x) + fabsf(a.y - b.y) + fabsf(a.z - b.z) + fabsf(a.w - b.w);
    }
    #pragma unroll
    for (int off = 32; off > 0; off >>= 1) s += __shfl_down(s, off);
    __shared__ float red[4];
    int lane = threadIdx.x & 63, wv = threadIdx.x >> 6;
    if (lane == 0) red[wv] = s;
    __syncthreads();
    if (threadIdx.x == 0) part[blockIdx.x] = red[0] + red[1] + red[2] + red[3];
}

// One thread per (j,d): quadratic-form coefficients (log2 domain), MSS weight folded.
// Also emits block partials of lqzx / lprior sums.
__global__ __launch_bounds__(256) void k_prep(const float* __restrict__ mu,
                                              const float* __restrict__ lv,
                                              const float* __restrict__ z,
                                              const int* __restrict__ nds,
                                              float* __restrict__ AC,
                                              float* __restrict__ part, int B) {
    int idx = blockIdx.x * 256 + threadIdx.x;
    int j = idx >> 4, d = idx & 15;
    float m = mu[idx], l = lv[idx], zz = z[idx];
    float is = __expf(-l);
    float a = -0.5f * LOG2E_F * is;
    float b = -2.0f * a * m;
    float ec = fmaf(-0.5f * LOG2E_F, l + LOG2PI_F, a * m * m);  // log2(C')

    float Nf = (float)(*nds);
    float Mf = (float)(B - 1);
    float strat = (Nf - Mf) / (Nf * Mf);
    float w = (j == 0) ? (1.0f / Nf) : ((j == 1) ? strat : (1.0f / Mf));

    float* row = AC + (size_t)j * ROWF;
    row[d] = a;
    row[16 + d] = b;
    row[32 + d] = w * exp2_(ec);
    float es = ec;
    es += __shfl_xor(es, 1); es += __shfl_xor(es, 2);
    es += __shfl_xor(es, 4); es += __shfl_xor(es, 8);
    if (d == 0) row[48] = w * exp2_(es);

    float t = zz - m;
    float ga = -0.5f * (fmaf(t * t, is, l) + LOG2PI_F);
    float gb = -0.5f * (fmaf(zz * zz, EXP_NEG1, 1.0f) + LOG2PI_F);
    #pragma unroll
    for (int off = 32; off > 0; off >>= 1) { ga += __shfl_down(ga, off); gb += __shfl_down(gb, off); }
    __shared__ float ra[4], rb[4];
    int lane = threadIdx.x & 63, wv = threadIdx.x >> 6;
    if (lane == 0) { ra[wv] = ga; rb[wv] = gb; }
    __syncthreads();
    if (threadIdx.x == 0) {
        part[blockIdx.x * 2 + 0] = ra[0] + ra[1] + ra[2] + ra[3];
        part[blockIdx.x * 2 + 1] = rb[0] + rb[1] + rb[2] + rb[3];
    }
}

#define DIM(AQ, BQ, CQ, comp, dd) \
    e = fmaf(AQ.comp, v2[dd], BQ.comp * v[dd]); s2 += e; \
    sd[dd] = fmaf(CQ.comp, exp2_(e), sd[dd]);

// grid (B/64, JSP), block 256 = 4 waves. ONE i PER LANE; j uniform per wave
// (row coefficients are wave-uniform -> scalar/broadcast loads, no LDS in hot loop,
//  no cross-lane reduction: each lane owns its i's 17 linear sums).
__global__ __launch_bounds__(256) void k_pair(const float* __restrict__ AC,
                                              const float* __restrict__ z,
                                              float* __restrict__ Racc, int B) {
    const int lane = threadIdx.x & 63;
    const int w    = threadIdx.x >> 6;
    const int i    = blockIdx.x * 64 + lane;
    const int jbase = blockIdx.y * (4 * JCW) + w * JCW;

    float v[16], v2[16];
    {
        const float4* zp = (const float4*)(z + (size_t)i * 16);
        float4 z0 = zp[0], z1 = zp[1], z2 = zp[2], z3 = zp[3];
        v[0]=z0.x; v[1]=z0.y; v[2]=z0.z; v[3]=z0.w;
        v[4]=z1.x; v[5]=z1.y; v[6]=z1.z; v[7]=z1.w;
        v[8]=z2.x; v[9]=z2.y; v[10]=z2.z; v[11]=z2.w;
        v[12]=z3.x; v[13]=z3.y; v[14]=z3.z; v[15]=z3.w;
        #pragma unroll
        for (int d = 0; d < 16; d++) v2[d] = v[d] * v[d];
    }

    float sd[16];
    #pragma unroll
    for (int d = 0; d < 16; d++) sd[d] = 0.0f;
    float stot = 0.0f;

    #pragma unroll 2
    for (int jj = 0; jj < JCW; ++jj) {
        const float* rp = AC + (size_t)(jbase + jj) * ROWF;   // wave-uniform
        const float4* r4 = (const float4*)rp;
        float4 A0 = r4[0], A1 = r4[1], A2 = r4[2], A3 = r4[3];
        float4 Bv0 = r4[4], Bv1 = r4[5], Bv2 = r4[6], Bv3 = r4[7];
        float4 Cv0 = r4[8], Cv1 = r4[9], Cv2 = r4[10], Cv3 = r4[11];
        float  P = rp[48];
        float s2 = 0.0f, e;
        DIM(A0, Bv0, Cv0, x, 0)  DIM(A0, Bv0, Cv0, y, 1)
        DIM(A0, Bv0, Cv0, z, 2)  DIM(A0, Bv0, Cv0, w, 3)
        DIM(A1, Bv1, Cv1, x, 4)  DIM(A1, Bv1, Cv1, y, 5)
        DIM(A1, Bv1, Cv1, z, 6)  DIM(A1, Bv1, Cv1, w, 7)
        DIM(A2, Bv2, Cv2, x, 8)  DIM(A2, Bv2, Cv2, y, 9)
        DIM(A2, Bv2, Cv2, z, 10) DIM(A2, Bv2, Cv2, w, 11)
        DIM(A3, Bv3, Cv3, x, 12) DIM(A3, Bv3, Cv3, y, 13)
        DIM(A3, Bv3, Cv3, z, 14) DIM(A3, Bv3, Cv3, w, 15)
        stot = fmaf(P, exp2_(s2), stot);
    }

    // 4 waves cover disjoint j for the same 64 i's: block-sum via LDS, then
    // coalesced c-major slab write.
    __shared__ float red[4][64][19];   // pad 19: odd stride -> 2-way max (free)
    red[w][lane][0] = stot;
    #pragma unroll
    for (int d = 0; d < 16; d++) red[w][lane][1 + d] = sd[d];
    __syncthreads();
    for (int t = threadIdx.x; t < 64 * 17; t += 256) {
        int c = t >> 6, il = t & 63;
        float s = red[0][il][c] + red[1][il][c] + red[2][il][c] + red[3][il][c];
        Racc[((size_t)blockIdx.y * 17 + c) * B + blockIdx.x * 64 + il] = s;
    }
}

// grid 32 x 256: lane -> i (64 per block), wave g -> c-subset. Sums the JSP slabs,
// applies the W[B-2,0] patch in-place, takes logs, emits block partials.
__global__ __launch_bounds__(256) void k_logs(const float* __restrict__ Racc,
                                              const float* __restrict__ AC,
                                              const float* __restrict__ z,
                                              const int* __restrict__ nds,
                                              float* __restrict__ part, int B) {
    const int lane = threadIdx.x & 63;
    const int g    = threadIdx.x >> 6;
    const int i    = blockIdx.x * 64 + lane;
    const int c0   = (g == 0) ? 0 : 1 + 4 * g;   // 0,5,9,13
    const int nc   = (g == 0) ? 5 : 4;

    float sums[5];
    #pragma unroll
    for (int k = 0; k < 5; k++) sums[k] = 0.0f;
    for (int s = 0; s < JSP; ++s) {
        #pragma unroll 5
        for (int k = 0; k < nc; ++k)
            sums[k] += Racc[((size_t)s * 17 + c0 + k) * B + i];
    }

    if (i == B - 2) {
        // prep folded w0 = 1/N into row 0, but W[B-2,0] = strat: add delta.
        const float* vv = z + (size_t)(B - 2) * 16;
        float Nf = (float)(*nds);
        float Mf = (float)(B - 1);
        float dwN = (Nf - 2.0f * Mf) / Mf;        // (strat - 1/N) * N
        for (int k = 0; k < nc; ++k) {
            int c = c0 + k;
            if (c == 0) {
                float s2 = 0.0f;
                #pragma unroll
                for (int d = 0; d < 16; d++) {
                    float vd = vv[d];
                    s2 += fmaf(AC[d], vd * vd, AC[16 + d] * vd);
                }
                sums[k] += dwN * AC[48] * exp2_(s2);
            } else {
                int d = c - 1;
                float vd = vv[d];
                float e = fmaf(AC[d], vd * vd, AC[16 + d] * vd);
                sums[k] += dwN * AC[32 + d] * exp2_(e);
            }
        }
    }

    float lqz = 0.0f, lqzp = 0.0f;
    for (int k = 0; k < nc; ++k) {
        float lg = log2_(sums[k]) * LN2_F;
        if (c0 + k == 0) lqz = lg; else lqzp += lg;
    }
    #pragma unroll
    for (int off = 32; off > 0; off >>= 1) {
        lqz  += __shfl_down(lqz, off);
        lqzp += __shfl_down(lqzp, off);
    }
    __shared__ float ra[4], rb[4];
    if (lane == 0) { ra[g] = lqz; rb[g] = lqzp; }
    __syncthreads();
    if (threadIdx.x == 0) {
        part[blockIdx.x * 2 + 0] = ra[0] + ra[1] + ra[2] + ra[3];
        part[blockIdx.x * 2 + 1] = rb[0] + rb[1] + rb[2] + rb[3];
    }
}

__global__ __launch_bounds__(256) void k_final(const float* __restrict__ ws,
                                               float* __restrict__ out,
                                               float invBF, float invB) {
    const float* reconPart = ws;
    const float* prepPart  = ws + 512;
    const float* logsPart  = ws + 768;
    int t = threadIdx.x;
    float rec = 0.0f, lqzx = 0.0f, lpr = 0.0f, lqz = 0.0f, lqzp = 0.0f;
    for (int k = t; k < 512; k += 256) rec += reconPart[k];
    if (t < 128) { lqzx = prepPart[2 * t]; lpr = prepPart[2 * t + 1]; }
    if (t < 32)  { lqz  = logsPart[2 * t]; lqzp = logsPart[2 * t + 1]; }
    #pragma unroll
    for (int off = 32; off > 0; off >>= 1) {
        rec += __shfl_down(rec, off);   lqzx += __shfl_down(lqzx, off);
        lpr += __shfl_down(lpr, off);   lqz  += __shfl_down(lqz, off);
        lqzp += __shfl_down(lqzp, off);
    }
    __shared__ float red[4][5];
    int lane = t & 63, wv = t >> 6;
    if (lane == 0) {
        red[wv][0] = rec; red[wv][1] = lqzx; red[wv][2] = lpr;
        red[wv][3] = lqz; red[wv][4] = lqzp;
    }
    __syncthreads();
    if (t == 0) {
        float R = red[0][0] + red[1][0] + red[2][0] + red[3][0];
        float X = red[0][1] + red[1][1] + red[2][1] + red[3][1];
        float P = red[0][2] + red[1][2] + red[2][2] + red[3][2];
        float Q = red[0][3] + red[1][3] + red[2][3] + red[3][3];
        float D = red[0][4] + red[1][4] + red[2][4] + red[3][4];
        out[0] = R * invBF + (X + 3.0f * Q - 3.0f * D - P) * invB;
    }
}

extern "C" void kernel_launch(void* const* d_in, const int* in_sizes, int n_in,
                              void* d_out, int out_size, void* d_ws, size_t ws_size,
                              hipStream_t stream) {
    const float* x   = (const float*)d_in[0];
    const float* rec = (const float*)d_in[1];
    const float* mu  = (const float*)d_in[2];
    const float* lv  = (const float*)d_in[3];
    const float* z   = (const float*)d_in[4];
    const int*   nds = (const int*)d_in[5];

    const int BD = in_sizes[2];        // B * 16
    const int B  = BD / 16;            // 2048
    const int BF = in_sizes[0];        // B * F
    const int n4 = BF / 4;

    float* ws        = (float*)d_ws;
    float* reconPart = ws;                         // 512
    float* prepPart  = ws + 512;                   // 256
    float* logsPart  = ws + 768;                   // 64
    float* AC        = ws + 1024;                  // B*52, 16B aligned
    float* Racc      = AC + (size_t)B * ROWF;      // JSP*17*B

    k_prep <<<BD / 256, 256, 0, stream>>>(mu, lv, z, nds, AC, prepPart, B);
    k_recon<<<512, 256, 0, stream>>>((const float4*)x, (const float4*)rec, reconPart, n4);
    dim3 gp(B / 64, JSP);
    k_pair <<<gp, 256, 0, stream>>>(AC, z, Racc, B);
    k_logs <<<B / 64, 256, 0, stream>>>(Racc, AC, z, nds, logsPart, B);
    k_final<<<1, 256, 0, stream>>>(ws, (float*)d_out, 1.0f / (float)BF, 1.0f / (float)B);
}